// Round 3
// baseline (815.599 us; speedup 1.0000x reference)
//
#include <hip/hip_runtime.h>
#include <math.h>

// ---------------- grid parameters ----------------
#define G     30
#define NC    (G*G*G)          // 27000 cells per batch
#define NCP1  (NC+1)
#define EXT   40.0f            // grid covers [-40,40]^3, outside clamps (proven safe)
#define SCALE 0.375f           // G/(2*EXT) = 30/80, exact in f32
#define HLO   2.6666665f       // <= true cell width 80/30 (conservative bound)
#define SLACK 0.01f            // covers d2 cancellation error (~1e-4) + cell-assign slop
#define BTH   1024             // build-kernel threads
#define QPB   256              // queries per search block

__device__ __forceinline__ int cell_coord(float x) {
    int c = (int)floorf((x + EXT) * SCALE);
    return min(G - 1, max(0, c));
}

// ---------------- build kernel: one block per batch ----------------
// dynamic LDS: hist[NC] + aux[BTH]  (112,096 B)
extern "C" __global__ void __launch_bounds__(BTH)
build_grid(const float* __restrict__ xyz, int mb,
           int* __restrict__ off_p, float4* __restrict__ sp, int* __restrict__ spidx)
{
    extern __shared__ int lds[];
    int* hist = lds;
    int* aux  = lds + NC;
    const int b   = blockIdx.x;
    const int tid = threadIdx.x;
    const float* P = xyz + (size_t)b * mb * 3;

    for (int i = tid; i < NC; i += BTH) hist[i] = 0;
    __syncthreads();
    for (int i = tid; i < mb; i += BTH) {
        const float x = P[i*3], y = P[i*3+1], z = P[i*3+2];
        const int c = (cell_coord(z)*G + cell_coord(y))*G + cell_coord(x);
        atomicAdd(&hist[c], 1);
    }
    __syncthreads();
    // chunked exclusive scan over NC cells
    const int CH = (NC + BTH - 1) / BTH;   // 27
    const int c0 = tid * CH;
    int s = 0;
    for (int j = 0; j < CH; ++j) { const int c = c0 + j; if (c < NC) s += hist[c]; }
    aux[tid] = s;
    __syncthreads();
    for (int off = 1; off < BTH; off <<= 1) {
        int v = aux[tid];
        if (tid >= off) v += aux[tid - off];
        __syncthreads();
        aux[tid] = v;
        __syncthreads();
    }
    int run = (tid == 0) ? 0 : aux[tid - 1];
    int* offb = off_p + (size_t)b * NCP1;
    for (int j = 0; j < CH; ++j) {
        const int c = c0 + j;
        if (c < NC) { const int h = hist[c]; offb[c] = run; hist[c] = run; run += h; }
    }
    if (tid == BTH - 1) offb[NC] = mb;
    __syncthreads();
    // scatter (cell-internal order arbitrary; search's lex-insert is order-invariant)
    for (int i = tid; i < mb; i += BTH) {
        const float x = P[i*3], y = P[i*3+1], z = P[i*3+2];
        const int c = (cell_coord(z)*G + cell_coord(y))*G + cell_coord(x);
        const int pos = atomicAdd(&hist[c], 1);
        float pn;
        {
#pragma clang fp contract(off)
            pn = (x * x + y * y) + z * z;      // matches np.sum(known*known,-1)
        }
        sp[(size_t)b*mb + pos]    = make_float4(x, y, z, pn);
        spidx[(size_t)b*mb + pos] = i;          // LOCAL index (tie-break domain)
    }
}

// ---------------- query binning: one block per batch ----------------
extern "C" __global__ void __launch_bounds__(BTH)
bin_queries(const float* __restrict__ nxyz, int nb, int* __restrict__ q_order)
{
    extern __shared__ int lds[];
    int* hist = lds;
    int* aux  = lds + NC;
    const int b = blockIdx.x, tid = threadIdx.x;
    const float* Q = nxyz + (size_t)b * nb * 3;

    for (int i = tid; i < NC; i += BTH) hist[i] = 0;
    __syncthreads();
    for (int i = tid; i < nb; i += BTH) {
        const int c = (cell_coord(Q[i*3+2])*G + cell_coord(Q[i*3+1]))*G + cell_coord(Q[i*3]);
        atomicAdd(&hist[c], 1);
    }
    __syncthreads();
    const int CH = (NC + BTH - 1) / BTH;
    const int c0 = tid * CH;
    int s = 0;
    for (int j = 0; j < CH; ++j) { const int c = c0 + j; if (c < NC) s += hist[c]; }
    aux[tid] = s;
    __syncthreads();
    for (int off = 1; off < BTH; off <<= 1) {
        int v = aux[tid];
        if (tid >= off) v += aux[tid - off];
        __syncthreads();
        aux[tid] = v;
        __syncthreads();
    }
    int run = (tid == 0) ? 0 : aux[tid - 1];
    for (int j = 0; j < CH; ++j) {
        const int c = c0 + j;
        if (c < NC) { const int h = hist[c]; hist[c] = run; run += h; }
    }
    __syncthreads();
    for (int i = tid; i < nb; i += BTH) {
        const int c = (cell_coord(Q[i*3+2])*G + cell_coord(Q[i*3+1]))*G + cell_coord(Q[i*3]);
        const int pos = atomicAdd(&hist[c], 1);
        q_order[(size_t)b*nb + pos] = i;
    }
}

// ---------------- search + interpolate ----------------
extern "C" __global__ void __launch_bounds__(QPB)
knn_grid_interp(const float* __restrict__ nxyz, const float* __restrict__ feats,
                const int* __restrict__ q_order, const int* __restrict__ off_p,
                const float4* __restrict__ sp, const int* __restrict__ spidx,
                float* __restrict__ out, int mb, int nb, int C)
{
    __shared__ float sW[3][QPB];
    __shared__ int   sF[3][QPB];
    __shared__ int   sRow[QPB];

    const int tid  = threadIdx.x;
    const int s0   = blockIdx.x * QPB;
    const int b    = s0 / nb;
    const int qloc = q_order[s0 + tid];
    const int row  = b * nb + qloc;

    const float qx = nxyz[(size_t)row*3 + 0];
    const float qy = nxyz[(size_t)row*3 + 1];
    const float qz = nxyz[(size_t)row*3 + 2];
    float qq;
    {
#pragma clang fp contract(off)
        qq = (qx * qx + qy * qy) + qz * qz;     // matches np.sum(query*query,-1)
    }
    const int cx = cell_coord(qx), cy = cell_coord(qy), cz = cell_coord(qz);
    const int cellofs = (cz*G + cy)*G + cx;
    const int*    offb = off_p + (size_t)b * NCP1;
    const float4* spb  = sp    + (size_t)b * mb;
    const int*    spib = spidx + (size_t)b * mb;

    float b0 = INFINITY, b1 = INFINITY, b2 = INFINITY;
    int   i0 = 0, i1 = 0, i2 = 0;
    bool  done = false;

    auto visit = [&](int dz, int dy, int dx) {
        if (done) return;
        const int zz = cz + dz, yy = cy + dy, xx = cx + dx;
        if (zz < 0 || zz >= G || yy < 0 || yy >= G || xx < 0 || xx >= G) return;
        const int c  = cellofs + (dz*G + dy)*G + dx;
        const int lo = offb[c], hi = offb[c + 1];
        for (int t = lo; t < hi; ++t) {
            const float4 Pt = spb[t];
            const int    pi = spib[t];
            const float dot = fmaf(qz, Pt.z, fmaf(qy, Pt.y, qx * Pt.x));
            const float d2  = fmaf(-2.0f, dot, qq) + Pt.w;   // EXACT reference rounding
            // lexicographic (d2, idx): matches top_k stable tie-break, visit-order invariant
            const bool c0 = (d2 < b0) || (d2 == b0 && pi < i0);
            const bool c1 = (d2 < b1) || (d2 == b1 && pi < i1);
            const bool c2 = (d2 < b2) || (d2 == b2 && pi < i2);
            const float nb2 = c1 ? b1 : (c2 ? d2 : b2); const int nj2 = c1 ? i1 : (c2 ? pi : i2);
            const float nb1 = c0 ? b0 : (c1 ? d2 : b1); const int nj1 = c0 ? i0 : (c1 ? pi : i1);
            const float nb0 = c0 ? d2 : b0;             const int nj0 = c0 ? pi : i0;
            b0 = nb0; b1 = nb1; b2 = nb2; i0 = nj0; i1 = nj1; i2 = nj2;
        }
    };

    for (int k = 0; k < G; ++k) {
        if (__all(done)) break;
        if (k == 0) {
            visit(0, 0, 0);
        } else {
            // ring (Chebyshev shell k): 6 faces, scalar-uniform offsets
            for (int sz = -k; sz <= k; sz += 2*k)
                for (int dy = -k; dy <= k; ++dy)
                    for (int dx = -k; dx <= k; ++dx) visit(sz, dy, dx);
            for (int sy = -k; sy <= k; sy += 2*k)
                for (int dz = -k+1; dz <= k-1; ++dz)
                    for (int dx = -k; dx <= k; ++dx) visit(dz, sy, dx);
            for (int sx = -k; sx <= k; sx += 2*k)
                for (int dz = -k+1; dz <= k-1; ++dz)
                    for (int dy = -k+1; dy <= k-1; ++dy) visit(dz, dy, sx);
        }
        // shells >= k+1 have true distance >= k*h; SLACK covers fp slop
        const float bnd = (float)k * HLO;
        done = (b2 < INFINITY) && (bnd * bnd > b2 + SLACK);
    }

    // weights (reference: sqrt(max(d2,0)), recip(+1e-8), normalize)
    const float da = sqrtf(fmaxf(b0, 0.0f));
    const float db = sqrtf(fmaxf(b1, 0.0f));
    const float dc = sqrtf(fmaxf(b2, 0.0f));
    const float ra = 1.0f / (da + 1e-8f);
    const float rb = 1.0f / (db + 1e-8f);
    const float rc = 1.0f / (dc + 1e-8f);
    float rs;
    {
#pragma clang fp contract(off)
        rs = (ra + rb) + rc;
    }
    sW[0][tid] = ra / rs;  sW[1][tid] = rb / rs;  sW[2][tid] = rc / rs;
    sF[0][tid] = b * mb + i0;  sF[1][tid] = b * mb + i1;  sF[2][tid] = b * mb + i2;
    sRow[tid]  = row;
    __syncthreads();

    // coalesced interpolation: wave per query, lanes = channels
    const int w = tid >> 6, l = tid & 63;
    for (int j = 0; j < QPB / 4; ++j) {
        const int q  = w * (QPB / 4) + j;
        const float wa = sW[0][q], wb = sW[1][q], wc = sW[2][q];
        const size_t ga = (size_t)sF[0][q] * C;
        const size_t gb = (size_t)sF[1][q] * C;
        const size_t gc = (size_t)sF[2][q] * C;
        const size_t go = (size_t)sRow[q] * C;
        for (int ch = l; ch < C; ch += 64) {
            out[go + ch] = wa * feats[ga + ch] + wb * feats[gb + ch] + wc * feats[gc + ch];
        }
    }
}

// ---------------- fallback: round-2 brute-force kernel ----------------
#define FTH 512
#define FWV 8
#define FRQ 4
#define FQPB 256
extern "C" __global__ void __launch_bounds__(FTH)
knn3_brute_kernel(const float* __restrict__ xyz,
                  const float* __restrict__ new_xyz,
                  const float* __restrict__ feats,
                  float* __restrict__ out,
                  int mb, int nb, int C)
{
    extern __shared__ float smem[];
    float4* s_pts = (float4*)smem;
    const int tid = threadIdx.x;
    const int w   = tid >> 6;
    const int l   = tid & 63;
    const int block_q0 = blockIdx.x * FQPB;
    const int batch    = block_q0 / nb;
    const int known0   = batch * mb;

    for (int p = tid; p < mb; p += FTH) {
        const float px = xyz[(size_t)(known0 + p) * 3 + 0];
        const float py = xyz[(size_t)(known0 + p) * 3 + 1];
        const float pz = xyz[(size_t)(known0 + p) * 3 + 2];
        float pn;
        {
#pragma clang fp contract(off)
            pn = (px * px + py * py) + pz * pz;
        }
        s_pts[p] = make_float4(px, py, pz, pn);
    }
    __syncthreads();

    float qx[FRQ], qy[FRQ], qz[FRQ], qq[FRQ];
#pragma unroll
    for (int r = 0; r < FRQ; ++r) {
        const int gq = block_q0 + r * 64 + l;
        qx[r] = new_xyz[(size_t)gq * 3 + 0];
        qy[r] = new_xyz[(size_t)gq * 3 + 1];
        qz[r] = new_xyz[(size_t)gq * 3 + 2];
        {
#pragma clang fp contract(off)
            qq[r] = (qx[r] * qx[r] + qy[r] * qy[r]) + qz[r] * qz[r];
        }
    }
    float b0[FRQ], b1[FRQ], b2[FRQ];
    int   i0[FRQ], i1[FRQ], i2[FRQ];
#pragma unroll
    for (int r = 0; r < FRQ; ++r) {
        b0[r] = INFINITY; b1[r] = INFINITY; b2[r] = INFINITY;
        i0[r] = 0; i1[r] = 0; i2[r] = 0;
    }
    const int clen = mb / FWV, p_beg = w * clen, p_end = p_beg + clen;
#pragma unroll 4
    for (int p = p_beg; p < p_end; ++p) {
        const float4 P = s_pts[p];
#pragma unroll
        for (int r = 0; r < FRQ; ++r) {
            const float dot = fmaf(qz[r], P.z, fmaf(qy[r], P.y, qx[r] * P.x));
            const float d2  = fmaf(-2.0f, dot, qq[r]) + P.w;
            const bool c0 = d2 < b0[r];
            const bool c1 = d2 < b1[r];
            const bool c2 = d2 < b2[r];
            const float n0 = fminf(d2, b0[r]);
            const float n1 = __builtin_amdgcn_fmed3f(d2, b0[r], b1[r]);
            const float n2 = __builtin_amdgcn_fmed3f(d2, b1[r], b2[r]);
            const int  j0 = c0 ? p : i0[r];
            const int  j1 = c0 ? i0[r] : (c1 ? p : i1[r]);
            const int  j2 = c1 ? i1[r] : (c2 ? p : i2[r]);
            b0[r] = n0; b1[r] = n1; b2[r] = n2;
            i0[r] = j0; i1[r] = j1; i2[r] = j2;
        }
    }
    __syncthreads();
    float* sB  = smem;
    int*   sI  = (int*)smem + 3 * FWV * FQPB;
    float* sFW = smem + 6 * FWV * FQPB;
    int*   sFI = (int*)sFW + 3 * FQPB;
#pragma unroll
    for (int r = 0; r < FRQ; ++r) {
        const int qb = r * 64 + l;
        sB[(0 * FWV + w) * FQPB + qb] = b0[r];
        sB[(1 * FWV + w) * FQPB + qb] = b1[r];
        sB[(2 * FWV + w) * FQPB + qb] = b2[r];
        sI[(0 * FWV + w) * FQPB + qb] = i0[r];
        sI[(1 * FWV + w) * FQPB + qb] = i1[r];
        sI[(2 * FWV + w) * FQPB + qb] = i2[r];
    }
    __syncthreads();
    if (tid < FQPB) {
        float mv0 = sB[(0 * FWV) * FQPB + tid];
        float mv1 = sB[(1 * FWV) * FQPB + tid];
        float mv2 = sB[(2 * FWV) * FQPB + tid];
        int   mi0 = sI[(0 * FWV) * FQPB + tid];
        int   mi1 = sI[(1 * FWV) * FQPB + tid];
        int   mi2 = sI[(2 * FWV) * FQPB + tid];
        for (int c = 1; c < FWV; ++c) {
#pragma unroll
            for (int k = 0; k < 3; ++k) {
                const float x  = sB[(k * FWV + c) * FQPB + tid];
                const int   xi = sI[(k * FWV + c) * FQPB + tid];
                const bool c0 = x < mv0;
                const bool c1 = x < mv1;
                const bool c2 = x < mv2;
                const float n0 = fminf(x, mv0);
                const float n1 = __builtin_amdgcn_fmed3f(x, mv0, mv1);
                const float n2 = __builtin_amdgcn_fmed3f(x, mv1, mv2);
                const int  j0 = c0 ? xi : mi0;
                const int  j1 = c0 ? mi0 : (c1 ? xi : mi1);
                const int  j2 = c1 ? mi1 : (c2 ? xi : mi2);
                mv0 = n0; mv1 = n1; mv2 = n2;
                mi0 = j0; mi1 = j1; mi2 = j2;
            }
        }
        const float da = sqrtf(fmaxf(mv0, 0.0f));
        const float db = sqrtf(fmaxf(mv1, 0.0f));
        const float dc = sqrtf(fmaxf(mv2, 0.0f));
        const float ra = 1.0f / (da + 1e-8f);
        const float rb = 1.0f / (db + 1e-8f);
        const float rc = 1.0f / (dc + 1e-8f);
        float rs;
        {
#pragma clang fp contract(off)
            rs = (ra + rb) + rc;
        }
        sFW[0 * FQPB + tid] = ra / rs;
        sFW[1 * FQPB + tid] = rb / rs;
        sFW[2 * FQPB + tid] = rc / rs;
        sFI[0 * FQPB + tid] = known0 + mi0;
        sFI[1 * FQPB + tid] = known0 + mi1;
        sFI[2 * FQPB + tid] = known0 + mi2;
    }
    __syncthreads();
    const int qpw = FQPB / FWV;
    for (int j = 0; j < qpw; ++j) {
        const int qi = w * qpw + j;
        const float wa = sFW[0 * FQPB + qi];
        const float wb = sFW[1 * FQPB + qi];
        const float wc = sFW[2 * FQPB + qi];
        const size_t ga = (size_t)sFI[0 * FQPB + qi] * C;
        const size_t gb = (size_t)sFI[1 * FQPB + qi] * C;
        const size_t gc = (size_t)sFI[2 * FQPB + qi] * C;
        const size_t go = (size_t)(block_q0 + qi) * C;
        for (int c = l; c < C; c += 64) {
            out[go + c] = wa * feats[ga + c] + wb * feats[gb + c] + wc * feats[gc + c];
        }
    }
}

extern "C" void kernel_launch(void* const* d_in, const int* in_sizes, int n_in,
                              void* d_out, int out_size, void* d_ws, size_t ws_size,
                              hipStream_t stream) {
    const float* xyz     = (const float*)d_in[0];
    const float* new_xyz = (const float*)d_in[2];
    const float* feats   = (const float*)d_in[4];
    float*       out     = (float*)d_out;

    const int n_known = in_sizes[0] / 3;
    const int B       = in_sizes[1];
    const int n_query = in_sizes[2] / 3;
    const int C       = in_sizes[4] / n_known;
    const int mb      = n_known / B;
    const int nb      = n_query / B;

    // workspace layout
    char* wp = (char*)d_ws;
    float4* sp    = (float4*)wp;            wp += (size_t)B * mb * sizeof(float4);
    int*   spidx  = (int*)wp;               wp += (size_t)B * mb * sizeof(int);
    int*   q_order= (int*)wp;               wp += (size_t)B * nb * sizeof(int);
    int*   off_p  = (int*)wp;               wp += (size_t)B * NCP1 * sizeof(int);
    const size_t need = (size_t)(wp - (char*)d_ws);

    const bool can_grid = (ws_size >= need) && (nb % QPB == 0) && (mb >= 3);

    if (can_grid) {
        const size_t lds_build = (size_t)(NC + BTH) * sizeof(int);
        build_grid <<<B, BTH, lds_build, stream>>>(xyz, mb, off_p, sp, spidx);
        bin_queries<<<B, BTH, lds_build, stream>>>(new_xyz, nb, q_order);
        knn_grid_interp<<<(B * nb) / QPB, QPB, 0, stream>>>(
            new_xyz, feats, q_order, off_p, sp, spidx, out, mb, nb, C);
    } else {
        const int grid = n_query / FQPB;
        size_t shmem = (size_t)mb * sizeof(float4);
        const size_t need_merge = (size_t)(6 * FWV * FQPB + 6 * FQPB) * sizeof(float);
        if (shmem < need_merge) shmem = need_merge;
        knn3_brute_kernel<<<grid, FTH, shmem, stream>>>(xyz, new_xyz, feats, out, mb, nb, C);
    }
}

// Round 4
// 214.169 us; speedup vs baseline: 3.8082x; 3.8082x over previous
//
#include <hip/hip_runtime.h>
#include <math.h>

// ---------------- grid parameters ----------------
#define G     30
#define NC    (G*G*G)          // 27000 cells per batch
#define NCP1  (NC+1)
#define EXT   40.0f            // grid covers [-40,40]^3, outside clamps (proven safe)
#define SCALE 0.375f           // G/(2*EXT) = 30/80, exact in f32
#define HLO   2.6666665f       // <= true cell width 80/30 (conservative bound)
#define SLACK 0.01f            // covers d2 cancellation error (~1e-3) + slop
#define BTH   1024             // build-kernel threads
#define QPB2  16               // queries per search block (16 groups of 16 lanes)

__device__ __forceinline__ int cell_coord(float x) {
    int c = (int)floorf((x + EXT) * SCALE);
    return min(G - 1, max(0, c));
}

__device__ __forceinline__ void ins3(unsigned long long k,
                                     unsigned long long& k0,
                                     unsigned long long& k1,
                                     unsigned long long& k2) {
    const bool c0 = k < k0, c1 = k < k1, c2 = k < k2;
    k2 = c1 ? k1 : (c2 ? k : k2);
    k1 = c0 ? k0 : (c1 ? k : k1);
    k0 = c0 ? k  : k0;
}

__device__ __forceinline__ unsigned long long shfl_xor_u64(unsigned long long v, int m) {
    unsigned lo = (unsigned)v, hi = (unsigned)(v >> 32);
    lo = __shfl_xor((int)lo, m, 64);
    hi = __shfl_xor((int)hi, m, 64);
    return ((unsigned long long)hi << 32) | lo;
}

// ---------------- build + bin (fused): grid = 2*B blocks ----------------
// blocks [0,B): bin points  -> off_p, sp(+pn), spidx, aabb
// blocks [B,2B): bin queries -> q_order
// dynamic LDS: hist[NC] + aux[BTH] + ab[6]
extern "C" __global__ void __launch_bounds__(BTH)
build_and_bin(const float* __restrict__ xyz, const float* __restrict__ nxyz,
              int mb, int nb,
              int* __restrict__ off_p, float4* __restrict__ sp,
              int* __restrict__ spidx, int* __restrict__ q_order,
              int* __restrict__ aabb_g)
{
    extern __shared__ int lds[];
    int* hist = lds;
    int* aux  = lds + NC;
    int* ab   = lds + NC + BTH;

    const int B    = (int)gridDim.x / 2;
    const bool isQ = (int)blockIdx.x >= B;
    const int b    = isQ ? (int)blockIdx.x - B : (int)blockIdx.x;
    const int tid  = threadIdx.x;
    const int n    = isQ ? nb : mb;
    const float* P = (isQ ? nxyz : xyz) + (size_t)b * n * 3;

    for (int i = tid; i < NC; i += BTH) hist[i] = 0;
    if (tid < 3) ab[tid] = G;            // mins
    else if (tid < 6) ab[tid] = -1;      // maxs
    __syncthreads();

    for (int i = tid; i < n; i += BTH) {
        const int c = (cell_coord(P[i*3+2])*G + cell_coord(P[i*3+1]))*G + cell_coord(P[i*3]);
        atomicAdd(&hist[c], 1);
    }
    __syncthreads();

    const int CH = (NC + BTH - 1) / BTH;   // 27
    const int c0 = tid * CH;

    if (!isQ) {
        // occupied-cell AABB from histogram
        int mnx = G, mny = G, mnz = G, mxx = -1, mxy = -1, mxz = -1;
        for (int j = 0; j < CH; ++j) {
            const int c = c0 + j;
            if (c < NC && hist[c] > 0) {
                const int x = c % G, y = (c / G) % G, z = c / (G * G);
                mnx = min(mnx, x); mxx = max(mxx, x);
                mny = min(mny, y); mxy = max(mxy, y);
                mnz = min(mnz, z); mxz = max(mxz, z);
            }
        }
        for (int m = 1; m < 64; m <<= 1) {
            mnx = min(mnx, __shfl_xor(mnx, m, 64)); mxx = max(mxx, __shfl_xor(mxx, m, 64));
            mny = min(mny, __shfl_xor(mny, m, 64)); mxy = max(mxy, __shfl_xor(mxy, m, 64));
            mnz = min(mnz, __shfl_xor(mnz, m, 64)); mxz = max(mxz, __shfl_xor(mxz, m, 64));
        }
        if ((tid & 63) == 0) {
            atomicMin(&ab[0], mnx); atomicMin(&ab[1], mny); atomicMin(&ab[2], mnz);
            atomicMax(&ab[3], mxx); atomicMax(&ab[4], mxy); atomicMax(&ab[5], mxz);
        }
    }
    __syncthreads();   // AABB done before hist is overwritten by scan

    if (!isQ && tid < 6) aabb_g[b * 8 + tid] = ab[tid];

    // chunked exclusive scan over NC cells
    int s = 0;
    for (int j = 0; j < CH; ++j) { const int c = c0 + j; if (c < NC) s += hist[c]; }
    aux[tid] = s;
    __syncthreads();
    for (int off = 1; off < BTH; off <<= 1) {
        int v = aux[tid];
        if (tid >= off) v += aux[tid - off];
        __syncthreads();
        aux[tid] = v;
        __syncthreads();
    }
    int run = (tid == 0) ? 0 : aux[tid - 1];
    int* offb = off_p + (size_t)b * NCP1;
    for (int j = 0; j < CH; ++j) {
        const int c = c0 + j;
        if (c < NC) {
            const int h = hist[c];
            if (!isQ) offb[c] = run;
            hist[c] = run;
            run += h;
        }
    }
    if (!isQ && tid == BTH - 1) offb[NC] = mb;
    __syncthreads();

    // scatter
    for (int i = tid; i < n; i += BTH) {
        const float x = P[i*3], y = P[i*3+1], z = P[i*3+2];
        const int c = (cell_coord(z)*G + cell_coord(y))*G + cell_coord(x);
        const int pos = atomicAdd(&hist[c], 1);
        if (isQ) {
            q_order[(size_t)b * nb + pos] = i;
        } else {
            float pn;
            {
#pragma clang fp contract(off)
                pn = (x * x + y * y) + z * z;   // matches np.sum(known*known,-1)
            }
            sp[(size_t)b * mb + pos]    = make_float4(x, y, z, pn);
            spidx[(size_t)b * mb + pos] = i;    // LOCAL index (tie-break domain)
        }
    }
}

// ---------------- search + interpolate: 16-lane group per query ----------------
extern "C" __global__ void __launch_bounds__(256)
knn_grid_interp2(const float* __restrict__ nxyz, const float* __restrict__ feats,
                 const int* __restrict__ q_order, const int* __restrict__ off_p,
                 const float4* __restrict__ sp, const int* __restrict__ spidx,
                 const int* __restrict__ aabb_g,
                 float* __restrict__ out, int mb, int nb, int C)
{
    __shared__ float sW[3][QPB2];
    __shared__ int   sF[3][QPB2];
    __shared__ int   sRow[QPB2];

    const int tid = threadIdx.x;
    const int g   = tid >> 4;          // group in block (query slot)
    const int sub = tid & 15;          // lane within group
    const int s0  = blockIdx.x * QPB2; // global q_order position of slot 0
    const int b   = s0 / nb;

    const int qloc = q_order[s0 + g];
    const int row  = b * nb + qloc;

    const float qx = nxyz[(size_t)row*3 + 0];
    const float qy = nxyz[(size_t)row*3 + 1];
    const float qz = nxyz[(size_t)row*3 + 2];
    float qq;
    {
#pragma clang fp contract(off)
        qq = (qx * qx + qy * qy) + qz * qz;   // matches np.sum(query*query,-1)
    }
    const int cx = cell_coord(qx), cy = cell_coord(qy), cz = cell_coord(qz);

    const int axlo = aabb_g[b*8+0], aylo = aabb_g[b*8+1], azlo = aabb_g[b*8+2];
    const int axhi = aabb_g[b*8+3], ayhi = aabb_g[b*8+4], azhi = aabb_g[b*8+5];

    const int*    offb = off_p + (size_t)b * NCP1;
    const float4* spb  = sp    + (size_t)b * mb;
    const int*    spib = spidx + (size_t)b * mb;

    unsigned long long a0 = ~0ull, a1 = ~0ull, a2 = ~0ull;   // per-lane top-3 keys
    unsigned long long r0 = ~0ull, r1 = ~0ull, r2 = ~0ull;   // merged result

    auto segment = [&](int zz, int yy, int xlo, int xhi) {
        if (xlo > xhi) return;
        const int cbase = (zz * G + yy) * G;
        const int lo = offb[cbase + xlo];
        const int hi = offb[cbase + xhi + 1];
        // alignment-based lane assignment: lane gets t with (t & 15) == sub
        for (int t = lo + ((sub - lo) & 15); t < hi; t += 16) {
            const float4 Pt = spb[t];
            const int    pi = spib[t];
            const float dot = fmaf(qz, Pt.z, fmaf(qy, Pt.y, qx * Pt.x));
            const float d2  = fmaf(-2.0f, dot, qq) + Pt.w;   // EXACT reference rounding
            const unsigned long long key =
                ((unsigned long long)__float_as_uint(d2) << 32) | (unsigned)pi;
            ins3(key, a0, a1, a2);   // lex (d2, idx): top_k stable tie-break
        }
    };

    // start at Chebyshev cell-distance to occupied AABB (shells below are empty)
    const int dxc = max(max(axlo - cx, cx - axhi), 0);
    const int dyc = max(max(aylo - cy, cy - ayhi), 0);
    const int dzc = max(max(azlo - cz, cz - azhi), 0);
    int k = max(dxc, max(dyc, dzc));

    for (; k <= 2 * G; ++k) {
        if (k == 0) {
            segment(cz, cy, cx, cx);
        } else {
            const int xlo = max(cx - k, axlo), xhi = min(cx + k, axhi);
            if (xlo <= xhi) {
                // side A: zz = cz±k, full rows
                for (int si = 0; si < 2; ++si) {
                    const int zz = si ? cz + k : cz - k;
                    if (zz >= azlo && zz <= azhi) {
                        const int ylo = max(cy - k, aylo), yhi = min(cy + k, ayhi);
                        for (int yy = ylo; yy <= yhi; ++yy) segment(zz, yy, xlo, xhi);
                    }
                }
                // side B: yy = cy±k, interior zz
                const int zlo = max(cz - k + 1, azlo), zhi = min(cz + k - 1, azhi);
                for (int si = 0; si < 2; ++si) {
                    const int yy = si ? cy + k : cy - k;
                    if (yy >= aylo && yy <= ayhi) {
                        for (int zz = zlo; zz <= zhi; ++zz) segment(zz, yy, xlo, xhi);
                    }
                }
                // singles: xx = cx±k, interior (zz, yy)
                const int ylo2 = max(cy - k + 1, aylo), yhi2 = min(cy + k - 1, ayhi);
                for (int si = 0; si < 2; ++si) {
                    const int xx = si ? cx + k : cx - k;
                    if (xx >= axlo && xx <= axhi) {
                        for (int zz = zlo; zz <= zhi; ++zz)
                            for (int yy = ylo2; yy <= yhi2; ++yy) segment(zz, yy, xx, xx);
                    }
                }
            }
        }
        // merged (precise) stop check: butterfly over the 16-lane group
        unsigned long long m0 = a0, m1 = a1, m2 = a2;
        for (int m = 1; m <= 8; m <<= 1) {
            const unsigned long long p0 = shfl_xor_u64(m0, m);
            const unsigned long long p1 = shfl_xor_u64(m1, m);
            const unsigned long long p2 = shfl_xor_u64(m2, m);
            ins3(p0, m0, m1, m2); ins3(p1, m0, m1, m2); ins3(p2, m0, m1, m2);
        }
        r0 = m0; r1 = m1; r2 = m2;
        // shells >= k+1 have true distance >= k*h; SLACK covers fp slop.
        const float d2b = __uint_as_float((unsigned)(m2 >> 32));  // NaN until 3 found
        const float bnd = (float)k * HLO;
        if (bnd * bnd > d2b + SLACK) break;   // false while d2b is NaN
    }

    // weights (reference: sqrt(max(d2,0)), recip(+1e-8), normalize)
    if (sub == 0) {
        const float d0 = __uint_as_float((unsigned)(r0 >> 32));
        const float d1 = __uint_as_float((unsigned)(r1 >> 32));
        const float d2v = __uint_as_float((unsigned)(r2 >> 32));
        const float da = sqrtf(fmaxf(d0, 0.0f));
        const float db = sqrtf(fmaxf(d1, 0.0f));
        const float dc = sqrtf(fmaxf(d2v, 0.0f));
        const float ra = 1.0f / (da + 1e-8f);
        const float rb = 1.0f / (db + 1e-8f);
        const float rc = 1.0f / (dc + 1e-8f);
        float rs;
        {
#pragma clang fp contract(off)
            rs = (ra + rb) + rc;
        }
        sW[0][g] = ra / rs;  sW[1][g] = rb / rs;  sW[2][g] = rc / rs;
        sF[0][g] = b * mb + (int)(unsigned)(r0 & 0xFFFFFFFFu);
        sF[1][g] = b * mb + (int)(unsigned)(r1 & 0xFFFFFFFFu);
        sF[2][g] = b * mb + (int)(unsigned)(r2 & 0xFFFFFFFFu);
        sRow[g]  = row;
    }
    __syncthreads();

    // interpolation: wave per 4 queries, lanes = channels (coalesced)
    const int wv = tid >> 6, ln = tid & 63;
    for (int j = 0; j < QPB2 / 4; ++j) {
        const int q = wv * (QPB2 / 4) + j;
        const float wa = sW[0][q], wb = sW[1][q], wc = sW[2][q];
        const size_t ga = (size_t)sF[0][q] * C;
        const size_t gb = (size_t)sF[1][q] * C;
        const size_t gc = (size_t)sF[2][q] * C;
        const size_t go = (size_t)sRow[q] * C;
        for (int ch = ln; ch < C; ch += 64) {
            out[go + ch] = wa * feats[ga + ch] + wb * feats[gb + ch] + wc * feats[gc + ch];
        }
    }
}

// ---------------- fallback: round-2 brute-force kernel ----------------
#define FTH 512
#define FWV 8
#define FRQ 4
#define FQPB 256
extern "C" __global__ void __launch_bounds__(FTH)
knn3_brute_kernel(const float* __restrict__ xyz,
                  const float* __restrict__ new_xyz,
                  const float* __restrict__ feats,
                  float* __restrict__ out,
                  int mb, int nb, int C)
{
    extern __shared__ float smem[];
    float4* s_pts = (float4*)smem;
    const int tid = threadIdx.x;
    const int w   = tid >> 6;
    const int l   = tid & 63;
    const int block_q0 = blockIdx.x * FQPB;
    const int batch    = block_q0 / nb;
    const int known0   = batch * mb;

    for (int p = tid; p < mb; p += FTH) {
        const float px = xyz[(size_t)(known0 + p) * 3 + 0];
        const float py = xyz[(size_t)(known0 + p) * 3 + 1];
        const float pz = xyz[(size_t)(known0 + p) * 3 + 2];
        float pn;
        {
#pragma clang fp contract(off)
            pn = (px * px + py * py) + pz * pz;
        }
        s_pts[p] = make_float4(px, py, pz, pn);
    }
    __syncthreads();

    float qx[FRQ], qy[FRQ], qz[FRQ], qq[FRQ];
#pragma unroll
    for (int r = 0; r < FRQ; ++r) {
        const int gq = block_q0 + r * 64 + l;
        qx[r] = new_xyz[(size_t)gq * 3 + 0];
        qy[r] = new_xyz[(size_t)gq * 3 + 1];
        qz[r] = new_xyz[(size_t)gq * 3 + 2];
        {
#pragma clang fp contract(off)
            qq[r] = (qx[r] * qx[r] + qy[r] * qy[r]) + qz[r] * qz[r];
        }
    }
    float b0[FRQ], b1[FRQ], b2[FRQ];
    int   i0[FRQ], i1[FRQ], i2[FRQ];
#pragma unroll
    for (int r = 0; r < FRQ; ++r) {
        b0[r] = INFINITY; b1[r] = INFINITY; b2[r] = INFINITY;
        i0[r] = 0; i1[r] = 0; i2[r] = 0;
    }
    const int clen = mb / FWV, p_beg = w * clen, p_end = p_beg + clen;
#pragma unroll 4
    for (int p = p_beg; p < p_end; ++p) {
        const float4 P = s_pts[p];
#pragma unroll
        for (int r = 0; r < FRQ; ++r) {
            const float dot = fmaf(qz[r], P.z, fmaf(qy[r], P.y, qx[r] * P.x));
            const float d2  = fmaf(-2.0f, dot, qq[r]) + P.w;
            const bool c0 = d2 < b0[r];
            const bool c1 = d2 < b1[r];
            const bool c2 = d2 < b2[r];
            const float n0 = fminf(d2, b0[r]);
            const float n1 = __builtin_amdgcn_fmed3f(d2, b0[r], b1[r]);
            const float n2 = __builtin_amdgcn_fmed3f(d2, b1[r], b2[r]);
            const int  j0 = c0 ? p : i0[r];
            const int  j1 = c0 ? i0[r] : (c1 ? p : i1[r]);
            const int  j2 = c1 ? i1[r] : (c2 ? p : i2[r]);
            b0[r] = n0; b1[r] = n1; b2[r] = n2;
            i0[r] = j0; i1[r] = j1; i2[r] = j2;
        }
    }
    __syncthreads();
    float* sB  = smem;
    int*   sI  = (int*)smem + 3 * FWV * FQPB;
    float* sFW = smem + 6 * FWV * FQPB;
    int*   sFI = (int*)sFW + 3 * FQPB;
#pragma unroll
    for (int r = 0; r < FRQ; ++r) {
        const int qb = r * 64 + l;
        sB[(0 * FWV + w) * FQPB + qb] = b0[r];
        sB[(1 * FWV + w) * FQPB + qb] = b1[r];
        sB[(2 * FWV + w) * FQPB + qb] = b2[r];
        sI[(0 * FWV + w) * FQPB + qb] = i0[r];
        sI[(1 * FWV + w) * FQPB + qb] = i1[r];
        sI[(2 * FWV + w) * FQPB + qb] = i2[r];
    }
    __syncthreads();
    if (tid < FQPB) {
        float mv0 = sB[(0 * FWV) * FQPB + tid];
        float mv1 = sB[(1 * FWV) * FQPB + tid];
        float mv2 = sB[(2 * FWV) * FQPB + tid];
        int   mi0 = sI[(0 * FWV) * FQPB + tid];
        int   mi1 = sI[(1 * FWV) * FQPB + tid];
        int   mi2 = sI[(2 * FWV) * FQPB + tid];
        for (int c = 1; c < FWV; ++c) {
#pragma unroll
            for (int kk = 0; kk < 3; ++kk) {
                const float x  = sB[(kk * FWV + c) * FQPB + tid];
                const int   xi = sI[(kk * FWV + c) * FQPB + tid];
                const bool c0 = x < mv0;
                const bool c1 = x < mv1;
                const bool c2 = x < mv2;
                const float n0 = fminf(x, mv0);
                const float n1 = __builtin_amdgcn_fmed3f(x, mv0, mv1);
                const float n2 = __builtin_amdgcn_fmed3f(x, mv1, mv2);
                const int  j0 = c0 ? xi : mi0;
                const int  j1 = c0 ? mi0 : (c1 ? xi : mi1);
                const int  j2 = c1 ? mi1 : (c2 ? xi : mi2);
                mv0 = n0; mv1 = n1; mv2 = n2;
                mi0 = j0; mi1 = j1; mi2 = j2;
            }
        }
        const float da = sqrtf(fmaxf(mv0, 0.0f));
        const float db = sqrtf(fmaxf(mv1, 0.0f));
        const float dc = sqrtf(fmaxf(mv2, 0.0f));
        const float ra = 1.0f / (da + 1e-8f);
        const float rb = 1.0f / (db + 1e-8f);
        const float rc = 1.0f / (dc + 1e-8f);
        float rs;
        {
#pragma clang fp contract(off)
            rs = (ra + rb) + rc;
        }
        sFW[0 * FQPB + tid] = ra / rs;
        sFW[1 * FQPB + tid] = rb / rs;
        sFW[2 * FQPB + tid] = rc / rs;
        sFI[0 * FQPB + tid] = known0 + mi0;
        sFI[1 * FQPB + tid] = known0 + mi1;
        sFI[2 * FQPB + tid] = known0 + mi2;
    }
    __syncthreads();
    const int qpw = FQPB / FWV;
    for (int j = 0; j < qpw; ++j) {
        const int qi = w * qpw + j;
        const float wa = sFW[0 * FQPB + qi];
        const float wb = sFW[1 * FQPB + qi];
        const float wc = sFW[2 * FQPB + qi];
        const size_t ga = (size_t)sFI[0 * FQPB + qi] * C;
        const size_t gb = (size_t)sFI[1 * FQPB + qi] * C;
        const size_t gc = (size_t)sFI[2 * FQPB + qi] * C;
        const size_t go = (size_t)(block_q0 + qi) * C;
        for (int c = l; c < C; c += 64) {
            out[go + c] = wa * feats[ga + c] + wb * feats[gb + c] + wc * feats[gc + c];
        }
    }
}

extern "C" void kernel_launch(void* const* d_in, const int* in_sizes, int n_in,
                              void* d_out, int out_size, void* d_ws, size_t ws_size,
                              hipStream_t stream) {
    const float* xyz     = (const float*)d_in[0];
    const float* new_xyz = (const float*)d_in[2];
    const float* feats   = (const float*)d_in[4];
    float*       out     = (float*)d_out;

    const int n_known = in_sizes[0] / 3;
    const int B       = in_sizes[1];
    const int n_query = in_sizes[2] / 3;
    const int C       = in_sizes[4] / n_known;
    const int mb      = n_known / B;
    const int nb      = n_query / B;

    // workspace layout
    char* wp = (char*)d_ws;
    float4* sp     = (float4*)wp;           wp += (size_t)B * mb * sizeof(float4);
    int*    spidx  = (int*)wp;              wp += (size_t)B * mb * sizeof(int);
    int*    q_ord  = (int*)wp;              wp += (size_t)B * nb * sizeof(int);
    int*    off_p  = (int*)wp;              wp += (size_t)B * NCP1 * sizeof(int);
    int*    aabb_g = (int*)wp;              wp += (size_t)B * 8 * sizeof(int);
    const size_t need = (size_t)(wp - (char*)d_ws);

    const bool can_grid = (ws_size >= need) && (nb % QPB2 == 0) && (mb >= 3);

    if (can_grid) {
        const size_t lds_build = (size_t)(NC + BTH + 8) * sizeof(int);
        build_and_bin<<<2 * B, BTH, lds_build, stream>>>(
            xyz, new_xyz, mb, nb, off_p, sp, spidx, q_ord, aabb_g);
        knn_grid_interp2<<<(B * nb) / QPB2, 256, 0, stream>>>(
            new_xyz, feats, q_ord, off_p, sp, spidx, aabb_g, out, mb, nb, C);
    } else {
        const int grid = n_query / FQPB;
        size_t shmem = (size_t)mb * sizeof(float4);
        const size_t need_merge = (size_t)(6 * FWV * FQPB + 6 * FQPB) * sizeof(float);
        if (shmem < need_merge) shmem = need_merge;
        knn3_brute_kernel<<<grid, FTH, shmem, stream>>>(xyz, new_xyz, feats, out, mb, nb, C);
    }
}

// Round 5
// 140.566 us; speedup vs baseline: 5.8022x; 1.5236x over previous
//
#include <hip/hip_runtime.h>
#include <math.h>

#define THREADS 512   // 8 waves per block
#define WAVES   8
#define RQ      2     // queries per lane
#define QPB     128   // queries per block = 64 * RQ
#define CHUNK   2048  // points staged per LDS pass (32 KB -> 2 blocks/CU)

// Brute-force 3-NN + interpolate, v5 (occupancy-fixed v2).
// Grid = n_query/128 = 512 blocks -> 2 blocks/CU, 16 waves/CU (4/SIMD).
// Points staged in 2048-point LDS chunks; wave w scans slice [w,w+1)*cnt/8 of
// each chunk for all 128 queries (RQ=2 per lane). Accumulators carry across
// chunks. Cross-wave candidate ranges interleave, so the 8-way merge is
// lexicographic (d2, idx) -- exactly top_k's stable tie-break.
// d2 rounding is EXACTLY the reference's: d2 = fma(-2,dot,qq) + pn,
// dot = ascending-k fma chain, norms contract-off left-to-right.
extern "C" __global__ void __launch_bounds__(THREADS)
knn3_v5(const float* __restrict__ xyz,
        const float* __restrict__ new_xyz,
        const float* __restrict__ feats,
        float* __restrict__ out,
        int mb, int nb, int C)
{
    extern __shared__ float smem[];
    float4* s_pts = (float4*)smem;                 // CHUNK float4 (32 KB)

    const int tid = threadIdx.x;
    const int w   = tid >> 6;
    const int l   = tid & 63;
    const int block_q0 = blockIdx.x * QPB;
    const int batch    = block_q0 / nb;
    const int known0   = batch * mb;

    // ---- load queries (RQ per lane) ----
    float qx[RQ], qy[RQ], qz[RQ], qq[RQ];
#pragma unroll
    for (int r = 0; r < RQ; ++r) {
        const int gq = block_q0 + r * 64 + l;
        qx[r] = new_xyz[(size_t)gq * 3 + 0];
        qy[r] = new_xyz[(size_t)gq * 3 + 1];
        qz[r] = new_xyz[(size_t)gq * 3 + 2];
        {
#pragma clang fp contract(off)
            qq[r] = (qx[r] * qx[r] + qy[r] * qy[r]) + qz[r] * qz[r];
        }
    }

    float b0[RQ], b1[RQ], b2[RQ];
    int   i0[RQ], i1[RQ], i2[RQ];
#pragma unroll
    for (int r = 0; r < RQ; ++r) {
        b0[r] = INFINITY; b1[r] = INFINITY; b2[r] = INFINITY;
        i0[r] = 0; i1[r] = 0; i2[r] = 0;
    }

    // ---- chunked scan ----
    const int nch = (mb + CHUNK - 1) / CHUNK;
    for (int c = 0; c < nch; ++c) {
        const int base = c * CHUNK;
        const int cnt  = min(CHUNK, mb - base);
        if (c > 0) __syncthreads();                // protect previous chunk reads

        // stage chunk: vectorized when 4-point-aligned (always true here)
        const float* src = xyz + (size_t)(known0 + base) * 3;
        if ((cnt & 3) == 0 && ((((size_t)(known0 + base) * 3) & 3) == 0)) {
            const float4* src4 = (const float4*)src;
            for (int i4 = tid; i4 * 4 < cnt; i4 += THREADS) {
                const float4 A = src4[i4 * 3 + 0];
                const float4 Bv = src4[i4 * 3 + 1];
                const float4 Cv = src4[i4 * 3 + 2];
                float px[4] = {A.x, A.w, Bv.z, Cv.y};
                float py[4] = {A.y, Bv.x, Bv.w, Cv.z};
                float pz[4] = {A.z, Bv.y, Cv.x, Cv.w};
#pragma unroll
                for (int j = 0; j < 4; ++j) {
                    float pn;
                    {
#pragma clang fp contract(off)
                        pn = (px[j] * px[j] + py[j] * py[j]) + pz[j] * pz[j];
                    }
                    s_pts[i4 * 4 + j] = make_float4(px[j], py[j], pz[j], pn);
                }
            }
        } else {
            for (int p = tid; p < cnt; p += THREADS) {
                const float px = src[p * 3 + 0];
                const float py = src[p * 3 + 1];
                const float pz = src[p * 3 + 2];
                float pn;
                {
#pragma clang fp contract(off)
                    pn = (px * px + py * py) + pz * pz;
                }
                s_pts[p] = make_float4(px, py, pz, pn);
            }
        }
        __syncthreads();

        // wave w scans its slice for all queries
        const int lo = (w * cnt) / WAVES;
        const int hi = ((w + 1) * cnt) / WAVES;
#pragma unroll 4
        for (int p = lo; p < hi; ++p) {
            const float4 P = s_pts[p];             // wave-uniform broadcast
            const int gp = base + p;               // batch-local candidate index
#pragma unroll
            for (int r = 0; r < RQ; ++r) {
                const float dot = fmaf(qz[r], P.z, fmaf(qy[r], P.y, qx[r] * P.x));
                const float d2  = fmaf(-2.0f, dot, qq[r]) + P.w;
                const bool c0 = d2 < b0[r];
                const bool c1 = d2 < b1[r];
                const bool c2 = d2 < b2[r];
                const float n0 = fminf(d2, b0[r]);
                const float n1 = __builtin_amdgcn_fmed3f(d2, b0[r], b1[r]);
                const float n2 = __builtin_amdgcn_fmed3f(d2, b1[r], b2[r]);
                const int  j0 = c0 ? gp : i0[r];
                const int  j1 = c0 ? i0[r] : (c1 ? gp : i1[r]);
                const int  j2 = c1 ? i1[r] : (c2 ? gp : i2[r]);
                b0[r] = n0; b1[r] = n1; b2[r] = n2;
                i0[r] = j0; i1[r] = j1; i2[r] = j2;
            }
        }
    }

    // ---- merge 8 per-wave partials (lexicographic (d2, idx)) ----
    __syncthreads();
    float* sB  = smem;                              // [3][WAVES][QPB]
    int*   sI  = (int*)smem + 3 * WAVES * QPB;      // [3][WAVES][QPB]
    float* sFW = smem + 6 * WAVES * QPB;            // [3][QPB]
    int*   sFI = (int*)sFW + 3 * QPB;               // [3][QPB]

#pragma unroll
    for (int r = 0; r < RQ; ++r) {
        const int qb = r * 64 + l;
        sB[(0 * WAVES + w) * QPB + qb] = b0[r];
        sB[(1 * WAVES + w) * QPB + qb] = b1[r];
        sB[(2 * WAVES + w) * QPB + qb] = b2[r];
        sI[(0 * WAVES + w) * QPB + qb] = i0[r];
        sI[(1 * WAVES + w) * QPB + qb] = i1[r];
        sI[(2 * WAVES + w) * QPB + qb] = i2[r];
    }
    __syncthreads();

    if (tid < QPB) {
        float mv0 = sB[(0 * WAVES) * QPB + tid];
        float mv1 = sB[(1 * WAVES) * QPB + tid];
        float mv2 = sB[(2 * WAVES) * QPB + tid];
        int   mi0 = sI[(0 * WAVES) * QPB + tid];
        int   mi1 = sI[(1 * WAVES) * QPB + tid];
        int   mi2 = sI[(2 * WAVES) * QPB + tid];
        for (int c = 1; c < WAVES; ++c) {
#pragma unroll
            for (int k = 0; k < 3; ++k) {
                const float x  = sB[(k * WAVES + c) * QPB + tid];
                const int   xi = sI[(k * WAVES + c) * QPB + tid];
                // lexicographic (d2, idx): wave ranges interleave across chunks
                const bool c0 = (x < mv0) || (x == mv0 && xi < mi0);
                const bool c1 = (x < mv1) || (x == mv1 && xi < mi1);
                const bool c2 = (x < mv2) || (x == mv2 && xi < mi2);
                const float n2 = c1 ? mv1 : (c2 ? x : mv2);
                const int   j2 = c1 ? mi1 : (c2 ? xi : mi2);
                const float n1 = c0 ? mv0 : (c1 ? x : mv1);
                const int   j1 = c0 ? mi0 : (c1 ? xi : mi1);
                const float n0 = c0 ? x : mv0;
                const int   j0 = c0 ? xi : mi0;
                mv0 = n0; mv1 = n1; mv2 = n2;
                mi0 = j0; mi1 = j1; mi2 = j2;
            }
        }

        // weights (reference: sqrt(max(d2,0)), recip(+1e-8), normalize)
        const float da = sqrtf(fmaxf(mv0, 0.0f));
        const float db = sqrtf(fmaxf(mv1, 0.0f));
        const float dc = sqrtf(fmaxf(mv2, 0.0f));
        const float ra = 1.0f / (da + 1e-8f);
        const float rb = 1.0f / (db + 1e-8f);
        const float rc = 1.0f / (dc + 1e-8f);
        float rs;
        {
#pragma clang fp contract(off)
            rs = (ra + rb) + rc;
        }
        sFW[0 * QPB + tid] = ra / rs;
        sFW[1 * QPB + tid] = rb / rs;
        sFW[2 * QPB + tid] = rc / rs;
        sFI[0 * QPB + tid] = known0 + mi0;
        sFI[1 * QPB + tid] = known0 + mi1;
        sFI[2 * QPB + tid] = known0 + mi2;
    }
    __syncthreads();

    // ---- coalesced interpolation: wave per 16 queries, lanes = channels ----
    const int qpw = QPB / WAVES;                    // 16
    for (int j = 0; j < qpw; ++j) {
        const int qi = w * qpw + j;
        const float wa = sFW[0 * QPB + qi];
        const float wb = sFW[1 * QPB + qi];
        const float wc = sFW[2 * QPB + qi];
        const size_t ga = (size_t)sFI[0 * QPB + qi] * C;
        const size_t gb = (size_t)sFI[1 * QPB + qi] * C;
        const size_t gc = (size_t)sFI[2 * QPB + qi] * C;
        const size_t go = (size_t)(block_q0 + qi) * C;
        for (int ch = l; ch < C; ch += 64) {
            out[go + ch] = wa * feats[ga + ch] + wb * feats[gb + ch] + wc * feats[gc + ch];
        }
    }
}

// ---------------- fallback: round-1 kernel (generic shapes) ----------------
#define FQPB 256
extern "C" __global__ void __launch_bounds__(FQPB)
knn3_fallback(const float* __restrict__ xyz,
              const float* __restrict__ new_xyz,
              const float* __restrict__ feats,
              float* __restrict__ out,
              int mb, int nb, int C)
{
    extern __shared__ float4 s_pts[];
    const int tid      = threadIdx.x;
    const int block_q0 = blockIdx.x * FQPB;
    const int batch    = block_q0 / nb;
    const int known0   = batch * mb;

    for (int p = tid; p < mb; p += FQPB) {
        const float px = xyz[(size_t)(known0 + p) * 3 + 0];
        const float py = xyz[(size_t)(known0 + p) * 3 + 1];
        const float pz = xyz[(size_t)(known0 + p) * 3 + 2];
        float pn;
        {
#pragma clang fp contract(off)
            pn = (px * px + py * py) + pz * pz;
        }
        s_pts[p] = make_float4(px, py, pz, pn);
    }
    __syncthreads();

    const int gq = block_q0 + tid;
    const float qx = new_xyz[(size_t)gq * 3 + 0];
    const float qy = new_xyz[(size_t)gq * 3 + 1];
    const float qz = new_xyz[(size_t)gq * 3 + 2];
    float qq;
    {
#pragma clang fp contract(off)
        qq = (qx * qx + qy * qy) + qz * qz;
    }
    float b0 = INFINITY, b1 = INFINITY, b2 = INFINITY;
    int   i0 = 0, i1 = 0, i2 = 0;
#pragma unroll 8
    for (int p = 0; p < mb; ++p) {
        const float4 P = s_pts[p];
        const float dot = fmaf(qz, P.z, fmaf(qy, P.y, qx * P.x));
        const float d2  = fmaf(-2.0f, dot, qq) + P.w;
        const bool c0 = d2 < b0;
        const bool c1 = d2 < b1;
        const bool c2 = d2 < b2;
        b2 = c1 ? b1 : (c2 ? d2 : b2);
        i2 = c1 ? i1 : (c2 ? p  : i2);
        b1 = c0 ? b0 : (c1 ? d2 : b1);
        i1 = c0 ? i0 : (c1 ? p  : i1);
        b0 = c0 ? d2 : b0;
        i0 = c0 ? p  : i0;
    }
    const float da = sqrtf(fmaxf(b0, 0.0f));
    const float db = sqrtf(fmaxf(b1, 0.0f));
    const float dc = sqrtf(fmaxf(b2, 0.0f));
    const float ra = 1.0f / (da + 1e-8f);
    const float rb = 1.0f / (db + 1e-8f);
    const float rc = 1.0f / (dc + 1e-8f);
    float rs;
    {
#pragma clang fp contract(off)
        rs = (ra + rb) + rc;
    }
    const float wa = ra / rs, wb = rb / rs, wc = rc / rs;
    const size_t ga = (size_t)(known0 + i0) * C;
    const size_t gb = (size_t)(known0 + i1) * C;
    const size_t gc = (size_t)(known0 + i2) * C;
    const size_t go = (size_t)gq * C;
    for (int ch = 0; ch < C; ++ch) {
        out[go + ch] = wa * feats[ga + ch] + wb * feats[gb + ch] + wc * feats[gc + ch];
    }
}

extern "C" void kernel_launch(void* const* d_in, const int* in_sizes, int n_in,
                              void* d_out, int out_size, void* d_ws, size_t ws_size,
                              hipStream_t stream) {
    const float* xyz     = (const float*)d_in[0];
    const float* new_xyz = (const float*)d_in[2];
    const float* feats   = (const float*)d_in[4];
    float*       out     = (float*)d_out;

    const int n_known = in_sizes[0] / 3;
    const int B       = in_sizes[1];
    const int n_query = in_sizes[2] / 3;
    const int C       = in_sizes[4] / n_known;
    const int mb      = n_known / B;
    const int nb      = n_query / B;

    if ((nb % QPB) == 0) {
        const size_t smem_chunk = (size_t)CHUNK * sizeof(float4);           // 32 KB
        const size_t smem_merge = (size_t)(6 * WAVES * QPB + 6 * QPB) * sizeof(float);
        const size_t shmem = smem_chunk > smem_merge ? smem_chunk : smem_merge;
        knn3_v5<<<n_query / QPB, THREADS, shmem, stream>>>(
            xyz, new_xyz, feats, out, mb, nb, C);
    } else {
        const size_t shmem = (size_t)mb * sizeof(float4);
        knn3_fallback<<<(n_query + FQPB - 1) / FQPB, FQPB, shmem, stream>>>(
            xyz, new_xyz, feats, out, mb, nb, C);
    }
}